// Round 7
// baseline (4472.894 us; speedup 1.0000x reference)
//
#include <hip/hip_runtime.h>
#include <math.h>
#include <stdint.h>

typedef float f32x4 __attribute__((ext_vector_type(4)));
typedef short short8 __attribute__((ext_vector_type(8)));

static constexpr int HWo   = 3136;   // 56*56
static constexpr int NB    = 8;
static constexpr int NP    = 3200;   // padded pixel/centroid count (25*128)
static constexpr int KDIM  = 1794;   // 1792 + 2 coord channels
static constexpr int KP1   = 1920;   // gemm1 K padded to 30*64 (even tile count)
static constexpr int ODIM  = 1792;   // gemm2 K = 28*64
static constexpr int NCENT = 3136;

__device__ __forceinline__ uint16_t f2bf(float f) {
  union { float f; uint32_t u; } v; v.f = f;
  uint32_t u = v.u;
  return (uint16_t)((u + 0x7FFFu + ((u >> 16) & 1u)) >> 16);   // RNE
}
__device__ __forceinline__ float bf2f(uint16_t h) {
  union { uint32_t u; float f; } v; v.u = ((uint32_t)h) << 16;
  return v.f;
}

// ---------------- one-time converts ----------------
__global__ __launch_bounds__(256) void convW_kernel(const float* __restrict__ W, uint16_t* __restrict__ Wh) {
  int idx = blockIdx.x * 256 + threadIdx.x;          // 1792*1920 exact
  int o = idx / KP1, k = idx % KP1;
  float v = (k < KDIM) ? W[(size_t)o * KDIM + k] : 0.f;
  Wh[idx] = f2bf(v);
}

__global__ __launch_bounds__(256) void convC_kernel(const float* __restrict__ C, uint16_t* __restrict__ Ct) {
  int idx = blockIdx.x * 256 + threadIdx.x;          // 3136*1792 exact
  int j = idx / ODIM, o = idx % ODIM;
  Ct[(size_t)j * ODIM + o] = f2bf(C[(size_t)o * NCENT + j]);
}

// cent[j] = |C_col_j|^2 for j<3136, 1e30 sentinel for padded rows
__global__ __launch_bounds__(256) void cent_kernel(const uint16_t* __restrict__ Ct, float* __restrict__ cent) {
  int t = threadIdx.x, lane = t & 63, wv = t >> 6;
  int row = blockIdx.x * 4 + wv;                     // 800 blocks -> 3200 rows
  if (row >= NCENT) { if (lane == 0) cent[row] = 1e30f; return; }
  const uint32_t* p = (const uint32_t*)(Ct + (size_t)row * ODIM);
  float s = 0.f;
  #pragma unroll
  for (int it = 0; it < 14; ++it) {
    uint32_t u = p[it * 64 + lane];
    float a = bf2f((uint16_t)(u & 0xFFFF)), b = bf2f((uint16_t)(u >> 16));
    s += a * a + b * b;
  }
  #pragma unroll
  for (int m = 1; m < 64; m <<= 1) s += __shfl_xor(s, m, 64);
  if (lane == 0) cent[row] = s;
}

// ---------------- pooling (all 3 levels, native res, fp32) ----------------
static constexpr int P1SZ = 256 * 3136;
static constexpr int P2SZ = 512 * 784;
static constexpr int P3SZ = 1024 * 196;

__device__ __forceinline__ float pool9f(const float* __restrict__ p, int S, int y, int x) {
  float s = 0.f;
  for (int dy = -1; dy <= 1; ++dy) {
    int yy = y + dy; if (yy < 0 || yy >= S) continue;
    for (int dx = -1; dx <= 1; ++dx) {
      int xx = x + dx; if (xx < 0 || xx >= S) continue;
      s += p[yy * S + xx];
    }
  }
  return s * (1.f / 9.f);
}

__global__ __launch_bounds__(256) void pool_kernel(const float* __restrict__ p1, const float* __restrict__ p2,
                                                   const float* __restrict__ p3, float* __restrict__ pooled, int b) {
  int idx = blockIdx.x * 256 + threadIdx.x;          // 1404928 exact
  const float* src; int S, loc;
  if (idx < P1SZ)              { src = p1 + (size_t)b * P1SZ; S = 56; loc = idx; }
  else if (idx < P1SZ + P2SZ)  { src = p2 + (size_t)b * P2SZ; S = 28; loc = idx - P1SZ; }
  else                         { src = p3 + (size_t)b * P3SZ; S = 14; loc = idx - P1SZ - P2SZ; }
  int c = loc / (S * S), hw = loc % (S * S);
  pooled[idx] = pool9f(src + (size_t)c * S * S, S, hw / S, hw % S);
}

// ---------------- assemble xcb bf16 [3200][1920] pixel-major; also zero feat ----------------
__global__ __launch_bounds__(256) void assemble_kernel(const float* __restrict__ pooled, uint16_t* __restrict__ xcb,
                                                       float* __restrict__ feat) {
  int idx = blockIdx.x * 256 + threadIdx.x;          // 3136*1920 exact
  if (idx < NP) feat[idx] = 0.f;                     // zero feat for gemm1 atomics
  int i = idx / KP1, ch = idx % KP1;
  int x = i % 56, y = i / 56;
  float v;
  if (ch < 256) {
    v = pooled[ch * 3136 + i];
  } else if (ch < 1792) {
    const float* base; int S; float scale, shift;
    if (ch < 768) { base = pooled + P1SZ + (ch - 256) * 784;          S = 28; scale = 0.5f;  shift = -0.25f;  }
    else          { base = pooled + P1SZ + P2SZ + (ch - 768) * 196;   S = 14; scale = 0.25f; shift = -0.375f; }
    float sx = x * scale + shift, sy = y * scale + shift;
    float fx0 = floorf(sx), fy0 = floorf(sy);
    float fx = sx - fx0, fy = sy - fy0;
    int x0 = (int)fx0, y0 = (int)fy0, x1 = x0 + 1, y1 = y0 + 1;
    x0 = x0 < 0 ? 0 : x0; x1 = x1 > S - 1 ? S - 1 : x1;
    y0 = y0 < 0 ? 0 : y0; y1 = y1 > S - 1 ? S - 1 : y1;
    float v00 = base[y0 * S + x0], v01 = base[y0 * S + x1];
    float v10 = base[y1 * S + x0], v11 = base[y1 * S + x1];
    v = (1.f - fy) * ((1.f - fx) * v00 + fx * v01) + fy * ((1.f - fx) * v10 + fx * v11);
  } else if (ch == 1792) v = -1.f + 2.f * x / 55.f;
  else if (ch == 1793)   v = -1.f + 2.f * y / 55.f;
  else                   v = 0.f;                    // K padding: MUST be zero
  xcb[idx] = f2bf(v);
}

// ---------------- shared GEMM building blocks ----------------
// LDS layout: slot (r, sc) holds global chunk sc^(r&7) of row r (XOR-8 swizzle, conflict-free).
// Staging thread t handles rows tr = (t>>3)+it*32, fixed chunk c=t&7 -> global chunk cg = c^(tr&7)
// (invariant across it since 32 = 0 mod 8); stores linearly at slot (it*256+t).
__device__ __forceinline__ void mfma_half(const uint16_t* As, const uint16_t* Bs,
                                          int wm, int wn, int l15, int quad, f32x4 (&acc)[4][4]) {
  #pragma unroll
  for (int kk = 0; kk < 2; ++kk) {
    int sc = (kk * 4 + quad) ^ (l15 & 7);
    short8 a[4], b[4];
    #pragma unroll
    for (int i = 0; i < 4; ++i) a[i] = *(const short8*)(As + (wm * 64 + i * 16 + l15) * 64 + sc * 8);
    #pragma unroll
    for (int j = 0; j < 4; ++j) b[j] = *(const short8*)(Bs + (wn * 64 + j * 16 + l15) * 64 + sc * 8);
    #pragma unroll
    for (int i = 0; i < 4; ++i)
      #pragma unroll
      for (int j = 0; j < 4; ++j)
        acc[i][j] = __builtin_amdgcn_mfma_f32_16x16x32_bf16(a[i], b[j], acc[i][j], 0, 0, 0);
  }
}

// Register-double-buffered K-loop: store tile k, prefetch tile k+1 into the other reg set, MFMA.
// KTOT must be an even multiple of 64. ldk in elements.
__device__ __forceinline__ void gemm_kloop(const uint16_t* __restrict__ pa, const uint16_t* __restrict__ pb,
                                           int ldk, int KTOT, uint16_t* As, uint16_t* Bs, int t,
                                           int wm, int wn, int l15, int quad, f32x4 (&acc)[4][4]) {
  uint4 sa[2][4], sb[2][4];
  #pragma unroll
  for (int it = 0; it < 4; ++it) {
    sa[0][it] = *(const uint4*)(pa + (size_t)it * 32 * ldk);
    sb[0][it] = *(const uint4*)(pb + (size_t)it * 32 * ldk);
  }
  #pragma unroll 1
  for (int k0 = 0; k0 < KTOT; k0 += 128) {
    // ---- half 0: store tile k0, prefetch k0+64, compute ----
    #pragma unroll
    for (int it = 0; it < 4; ++it) {
      *(uint4*)(As + (it * 256 + t) * 8) = sa[0][it];
      *(uint4*)(Bs + (it * 256 + t) * 8) = sb[0][it];
    }
    __syncthreads();
    #pragma unroll
    for (int it = 0; it < 4; ++it) {
      sa[1][it] = *(const uint4*)(pa + k0 + 64 + (size_t)it * 32 * ldk);
      sb[1][it] = *(const uint4*)(pb + k0 + 64 + (size_t)it * 32 * ldk);
    }
    mfma_half(As, Bs, wm, wn, l15, quad, acc);
    __syncthreads();
    // ---- half 1: store tile k0+64, prefetch k0+128, compute ----
    #pragma unroll
    for (int it = 0; it < 4; ++it) {
      *(uint4*)(As + (it * 256 + t) * 8) = sa[1][it];
      *(uint4*)(Bs + (it * 256 + t) * 8) = sb[1][it];
    }
    __syncthreads();
    if (k0 + 128 < KTOT) {
      #pragma unroll
      for (int it = 0; it < 4; ++it) {
        sa[0][it] = *(const uint4*)(pa + k0 + 128 + (size_t)it * 32 * ldk);
        sb[0][it] = *(const uint4*)(pb + k0 + 128 + (size_t)it * 32 * ldk);
      }
    }
    mfma_half(As, Bs, wm, wn, l15, quad, acc);
    __syncthreads();
  }
}

__device__ __forceinline__ void ins3(float v, float& a, float& b, float& c) {
  if (v < c) {
    if (v < b) { c = b; if (v < a) { b = a; a = v; } else { b = v; } }
    else { c = v; }
  }
}

// ---------------- GEMM1: phi_t[i][o] = W[o][:]·xc[i][:] + bias[o]; feat[i] += |phi_i|^2 ----------------
__global__ __launch_bounds__(256) void gemm1_mfma(const uint16_t* __restrict__ Wh, const float* __restrict__ bias,
                                                  const uint16_t* __restrict__ xcb, uint16_t* __restrict__ phi_t,
                                                  float* __restrict__ feat) {
  __shared__ uint16_t As[128 * 64];
  __shared__ uint16_t Bs[128 * 64];
  int t = threadIdx.x;
  int row0 = blockIdx.y * 128;     // o
  int col0 = blockIdx.x * 128;     // pixel
  int lane = t & 63, wv = t >> 6, wm = wv & 1, wn = wv >> 1;
  int l15 = lane & 15, quad = lane >> 4;
  int tr = t >> 3, cg = (t & 7) ^ (tr & 7);
  f32x4 acc[4][4] = {};
  gemm_kloop(Wh + (size_t)(row0 + tr) * KP1 + cg * 8,
             xcb + (size_t)(col0 + tr) * KP1 + cg * 8,
             KP1, KP1, As, Bs, t, wm, wn, l15, quad, acc);
  // D: col(l15)=pixel, row(quad*4+reg)=o
  float sq[4] = {0.f, 0.f, 0.f, 0.f};
  #pragma unroll
  for (int i = 0; i < 4; ++i) {
    int ob = row0 + wm * 64 + i * 16 + quad * 4;
    float4 bv = *(const float4*)&bias[ob];
    #pragma unroll
    for (int j = 0; j < 4; ++j) {
      int pix = col0 + wn * 64 + j * 16 + l15;
      float v0 = acc[i][j][0] + bv.x, v1 = acc[i][j][1] + bv.y;
      float v2 = acc[i][j][2] + bv.z, v3 = acc[i][j][3] + bv.w;
      ushort4 u; u.x = f2bf(v0); u.y = f2bf(v1); u.z = f2bf(v2); u.w = f2bf(v3);
      *(ushort4*)&phi_t[(size_t)pix * ODIM + ob] = u;
      sq[j] += v0 * v0 + v1 * v1 + v2 * v2 + v3 * v3;
    }
  }
  #pragma unroll
  for (int j = 0; j < 4; ++j) {
    sq[j] += __shfl_xor(sq[j], 16, 64);
    sq[j] += __shfl_xor(sq[j], 32, 64);
  }
  if (quad == 0) {
    #pragma unroll
    for (int j = 0; j < 4; ++j)
      atomicAdd(&feat[col0 + wn * 64 + j * 16 + l15], sq[j]);
  }
}

// ---------------- GEMM2 + fused top-3 (pixel-sequential, spill-free epilogue) ----------------
__global__ __launch_bounds__(256) void gemm2_mfma(const uint16_t* __restrict__ phi_t, const uint16_t* __restrict__ Ct,
                                                  const float* __restrict__ cent, float* __restrict__ part) {
  __shared__ uint16_t As[128 * 64];
  __shared__ uint16_t Bs[128 * 64];
  int t = threadIdx.x;
  int row0 = blockIdx.y * 128;     // pixel
  int col0 = blockIdx.x * 128;     // centroid
  int lane = t & 63, wv = t >> 6, wm = wv & 1, wn = wv >> 1;
  int l15 = lane & 15, quad = lane >> 4;
  int tr = t >> 3, cg = (t & 7) ^ (tr & 7);
  f32x4 acc[4][4] = {};
  gemm_kloop(phi_t + (size_t)(row0 + tr) * ODIM + cg * 8,
             Ct + (size_t)(col0 + tr) * ODIM + cg * 8,
             ODIM, ODIM, As, Bs, t, wm, wn, l15, quad, acc);
  // D: col(l15)=centroid q, row(quad*4+reg)=pixel p. Pixel-sequential top-3 (no spill).
  float cv0 = cent[col0 + wn * 64 +  0 + l15];
  float cv1 = cent[col0 + wn * 64 + 16 + l15];
  float cv2 = cent[col0 + wn * 64 + 32 + l15];
  float cv3 = cent[col0 + wn * 64 + 48 + l15];
  int cb = blockIdx.x * 2 + wn;                  // [0,50)
  #pragma unroll
  for (int i = 0; i < 4; ++i) {
    #pragma unroll
    for (int r = 0; r < 4; ++r) {
      float t0 = 1e30f, t1 = 1e30f, t2 = 1e30f;
      ins3(cv0 - 2.f * acc[i][0][r], t0, t1, t2);
      ins3(cv1 - 2.f * acc[i][1][r], t0, t1, t2);
      ins3(cv2 - 2.f * acc[i][2][r], t0, t1, t2);
      ins3(cv3 - 2.f * acc[i][3][r], t0, t1, t2);
      #pragma unroll
      for (int m = 1; m <= 8; m <<= 1) {
        float u0 = __shfl_xor(t0, m, 64);
        float u1 = __shfl_xor(t1, m, 64);
        float u2 = __shfl_xor(t2, m, 64);
        ins3(u0, t0, t1, t2); ins3(u1, t0, t1, t2); ins3(u2, t0, t1, t2);
      }
      if (l15 == 0) {
        int p = row0 + wm * 64 + i * 16 + quad * 4 + r;
        float* pp = part + ((size_t)p * 50 + cb) * 3;
        pp[0] = t0; pp[1] = t1; pp[2] = t2;
      }
    }
  }
}

// ---------------- merge 50 partial top-3 + softmin score, one wave per row ----------------
__global__ __launch_bounds__(256) void merge_score(const float* __restrict__ part, const float* __restrict__ feat,
                                                   float* __restrict__ out, int b) {
  int t = threadIdx.x, lane = t & 63, wv = t >> 6;
  int row = blockIdx.x * 4 + wv;                   // 784*4 = 3136
  float t0 = 1e30f, t1 = 1e30f, t2 = 1e30f;
  if (lane < 50) {
    const float* p = part + ((size_t)row * 50 + lane) * 3;
    ins3(p[0], t0, t1, t2); ins3(p[1], t0, t1, t2); ins3(p[2], t0, t1, t2);
  }
  #pragma unroll
  for (int m = 1; m < 64; m <<= 1) {
    float u0 = __shfl_xor(t0, m, 64);
    float u1 = __shfl_xor(t1, m, 64);
    float u2 = __shfl_xor(t2, m, 64);
    ins3(u0, t0, t1, t2); ins3(u1, t0, t1, t2); ins3(u2, t0, t1, t2);
  }
  if (lane == 0) {
    float ft = feat[row];
    float v0 = sqrtf(fmaxf(ft + t0, 0.f));
    float v1 = sqrtf(fmaxf(ft + t1, 0.f));
    float v2 = sqrtf(fmaxf(ft + t2, 0.f));
    float w0 = 1.f / (1.f + expf(v0 - v1) + expf(v0 - v2));
    out[b * HWo + row] = v0 * w0;
  }
}

// ---------------- launch ----------------
extern "C" void kernel_launch(void* const* d_in, const int* in_sizes, int n_in,
                              void* d_out, int out_size, void* d_ws, size_t ws_size,
                              hipStream_t stream) {
  const float* p1   = (const float*)d_in[0];
  const float* p2   = (const float*)d_in[1];
  const float* p3   = (const float*)d_in[2];
  const float* Wm   = (const float*)d_in[3];
  const float* bias = (const float*)d_in[4];
  const float* Cm   = (const float*)d_in[5];
  float* out = (float*)d_out;

  // workspace (~50 MB), 256B-aligned slices
  char* ws = (char*)d_ws;
  size_t off = 0;
  uint16_t* Wh     = (uint16_t*)(ws + off); off += (size_t)ODIM * KP1 * 2;          // 6,881,280
  uint16_t* Ct     = (uint16_t*)(ws + off); off += (size_t)NP * ODIM * 2;           // 11,468,800
  float*    cent   = (float*)(ws + off);    off += 16384;
  float*    feat   = (float*)(ws + off);    off += 16384;
  float*    part   = (float*)(ws + off);    off += (size_t)NP * 50 * 3 * 4;         // 1,920,000
  float*    pooled = (float*)(ws + off);    off += (size_t)(P1SZ + P2SZ + P3SZ) * 4;// 5,619,712
  uint16_t* xcb    = (uint16_t*)(ws + off); off += (size_t)NP * KP1 * 2;            // 12,288,000
  uint16_t* phi_t  = (uint16_t*)(ws + off); off += (size_t)NP * ODIM * 2;           // 11,468,800

  convW_kernel<<<(ODIM * KP1) / 256, 256, 0, stream>>>(Wm, Wh);
  convC_kernel<<<(NCENT * ODIM) / 256, 256, 0, stream>>>(Cm, Ct);
  cent_kernel<<<NP / 4, 256, 0, stream>>>(Ct, cent);

  for (int b = 0; b < NB; ++b) {
    pool_kernel<<<(P1SZ + P2SZ + P3SZ) / 256, 256, 0, stream>>>(p1, p2, p3, pooled, b);
    assemble_kernel<<<(HWo * KP1) / 256, 256, 0, stream>>>(pooled, xcb, feat);
    gemm1_mfma<<<dim3(NP / 128, ODIM / 128), 256, 0, stream>>>(Wh, bias, xcb, phi_t, feat);
    gemm2_mfma<<<dim3(NP / 128, NP / 128), 256, 0, stream>>>(phi_t, Ct, cent, part);
    merge_score<<<784, 256, 0, stream>>>(part, feat, out, b);
  }
}

// Round 8
// 2541.154 us; speedup vs baseline: 1.7602x; 1.7602x over previous
//
#include <hip/hip_runtime.h>
#include <math.h>
#include <stdint.h>

typedef float f32x4 __attribute__((ext_vector_type(4)));
typedef short short8 __attribute__((ext_vector_type(8)));

static constexpr int HWo   = 3136;   // 56*56
static constexpr int NB    = 8;
static constexpr int NP    = 3200;   // padded pixel/centroid count (25*128)
static constexpr int KDIM  = 1794;   // 1792 + 2 coord channels
static constexpr int KP1   = 1856;   // gemm1 K padded to 29*64
static constexpr int ODIM  = 1792;   // gemm2 K = 28*64
static constexpr int NCENT = 3136;

__device__ __forceinline__ uint16_t f2bf(float f) {
  union { float f; uint32_t u; } v; v.f = f;
  uint32_t u = v.u;
  return (uint16_t)((u + 0x7FFFu + ((u >> 16) & 1u)) >> 16);   // RNE
}
__device__ __forceinline__ float bf2f(uint16_t h) {
  union { uint32_t u; float f; } v; v.u = ((uint32_t)h) << 16;
  return v.f;
}

// ---------------- one-time converts ----------------
__global__ __launch_bounds__(256) void convW_kernel(const float* __restrict__ W, uint16_t* __restrict__ Wh) {
  int idx = blockIdx.x * 256 + threadIdx.x;          // 1792*1856 exact
  int o = idx / KP1, k = idx % KP1;
  float v = (k < KDIM) ? W[(size_t)o * KDIM + k] : 0.f;
  Wh[idx] = f2bf(v);
}

__global__ __launch_bounds__(256) void convC_kernel(const float* __restrict__ C, uint16_t* __restrict__ Ct) {
  int idx = blockIdx.x * 256 + threadIdx.x;          // 3136*1792 exact
  int j = idx / ODIM, o = idx % ODIM;
  Ct[(size_t)j * ODIM + o] = f2bf(C[(size_t)o * NCENT + j]);
}

// cent[j] = |C_col_j|^2 for j<3136, 1e30 sentinel for padded rows
__global__ __launch_bounds__(256) void cent_kernel(const uint16_t* __restrict__ Ct, float* __restrict__ cent) {
  int t = threadIdx.x, lane = t & 63, wv = t >> 6;
  int row = blockIdx.x * 4 + wv;                     // 800 blocks -> 3200 rows
  if (row >= NCENT) { if (lane == 0) cent[row] = 1e30f; return; }
  const uint32_t* p = (const uint32_t*)(Ct + (size_t)row * ODIM);
  float s = 0.f;
  #pragma unroll
  for (int it = 0; it < 14; ++it) {
    uint32_t u = p[it * 64 + lane];
    float a = bf2f((uint16_t)(u & 0xFFFF)), b = bf2f((uint16_t)(u >> 16));
    s += a * a + b * b;
  }
  #pragma unroll
  for (int m = 1; m < 64; m <<= 1) s += __shfl_xor(s, m, 64);
  if (lane == 0) cent[row] = s;
}

// ---------------- pooling (all 3 levels, native res, fp32) ----------------
static constexpr int P1SZ = 256 * 3136;
static constexpr int P2SZ = 512 * 784;
static constexpr int P3SZ = 1024 * 196;

__device__ __forceinline__ float pool9f(const float* __restrict__ p, int S, int y, int x) {
  float s = 0.f;
  for (int dy = -1; dy <= 1; ++dy) {
    int yy = y + dy; if (yy < 0 || yy >= S) continue;
    for (int dx = -1; dx <= 1; ++dx) {
      int xx = x + dx; if (xx < 0 || xx >= S) continue;
      s += p[yy * S + xx];
    }
  }
  return s * (1.f / 9.f);
}

__global__ __launch_bounds__(256) void pool_kernel(const float* __restrict__ p1, const float* __restrict__ p2,
                                                   const float* __restrict__ p3, float* __restrict__ pooled, int b) {
  int idx = blockIdx.x * 256 + threadIdx.x;          // 1404928 exact
  const float* src; int S, loc;
  if (idx < P1SZ)              { src = p1 + (size_t)b * P1SZ; S = 56; loc = idx; }
  else if (idx < P1SZ + P2SZ)  { src = p2 + (size_t)b * P2SZ; S = 28; loc = idx - P1SZ; }
  else                         { src = p3 + (size_t)b * P3SZ; S = 14; loc = idx - P1SZ - P2SZ; }
  int c = loc / (S * S), hw = loc % (S * S);
  pooled[idx] = pool9f(src + (size_t)c * S * S, S, hw / S, hw % S);
}

// ---------------- assemble xcb bf16 [3200][1856] pixel-major; also zero feat ----------------
__global__ __launch_bounds__(256) void assemble_kernel(const float* __restrict__ pooled, uint16_t* __restrict__ xcb,
                                                       float* __restrict__ feat) {
  int idx = blockIdx.x * 256 + threadIdx.x;          // 3136*1856 exact
  if (idx < NP) feat[idx] = 0.f;                     // zero feat for gemm1 atomics
  int i = idx / KP1, ch = idx % KP1;
  int x = i % 56, y = i / 56;
  float v;
  if (ch < 256) {
    v = pooled[ch * 3136 + i];
  } else if (ch < 1792) {
    const float* base; int S; float scale, shift;
    if (ch < 768) { base = pooled + P1SZ + (ch - 256) * 784;          S = 28; scale = 0.5f;  shift = -0.25f;  }
    else          { base = pooled + P1SZ + P2SZ + (ch - 768) * 196;   S = 14; scale = 0.25f; shift = -0.375f; }
    float sx = x * scale + shift, sy = y * scale + shift;
    float fx0 = floorf(sx), fy0 = floorf(sy);
    float fx = sx - fx0, fy = sy - fy0;
    int x0 = (int)fx0, y0 = (int)fy0, x1 = x0 + 1, y1 = y0 + 1;
    x0 = x0 < 0 ? 0 : x0; x1 = x1 > S - 1 ? S - 1 : x1;
    y0 = y0 < 0 ? 0 : y0; y1 = y1 > S - 1 ? S - 1 : y1;
    float v00 = base[y0 * S + x0], v01 = base[y0 * S + x1];
    float v10 = base[y1 * S + x0], v11 = base[y1 * S + x1];
    v = (1.f - fy) * ((1.f - fx) * v00 + fx * v01) + fy * ((1.f - fx) * v10 + fx * v11);
  } else if (ch == 1792) v = -1.f + 2.f * x / 55.f;
  else if (ch == 1793)   v = -1.f + 2.f * y / 55.f;
  else                   v = 0.f;                    // K padding: MUST be zero
  xcb[idx] = f2bf(v);
}

__device__ __forceinline__ void ins3(float v, float& a, float& b, float& c) {
  if (v < c) {
    if (v < b) { c = b; if (v < a) { b = a; a = v; } else { b = v; } }
    else { c = v; }
  }
}

// ---------------- GEMM1: phi_t[i][o] = W[o][:]·xc[i][:] + bias[o]; feat[i] += |phi_i|^2 ----------------
// Round-4-proven staging: per-iter VGPR loads -> padded LDS [72], single buffer.
__global__ __launch_bounds__(256) void gemm1_mfma(const uint16_t* __restrict__ Wh, const float* __restrict__ bias,
                                                  const uint16_t* __restrict__ xcb, uint16_t* __restrict__ phi_t,
                                                  float* __restrict__ feat) {
  __shared__ uint16_t As[128][72];   // +8 pad: benign 2.4% store-conflict tax (measured r4)
  __shared__ uint16_t Bs[128][72];
  int t = threadIdx.x;
  int row0 = blockIdx.y * 128;     // o
  int col0 = blockIdx.x * 128;     // pixel
  int lane = t & 63, wv = t >> 6, wm = wv & 1, wn = wv >> 1;
  int l15 = lane & 15, quad = lane >> 4;
  f32x4 acc[4][4] = {};
  for (int k0 = 0; k0 < KP1; k0 += 64) {
    #pragma unroll
    for (int it = 0; it < 4; ++it) {
      int idx = it * 256 + t;
      int r = idx >> 3, kc = idx & 7;
      *(uint4*)&As[r][kc * 8] = *(const uint4*)&Wh[(size_t)(row0 + r) * KP1 + k0 + kc * 8];
      *(uint4*)&Bs[r][kc * 8] = *(const uint4*)&xcb[(size_t)(col0 + r) * KP1 + k0 + kc * 8];
    }
    __syncthreads();
    #pragma unroll
    for (int kk = 0; kk < 2; ++kk) {
      int ko = kk * 32 + quad * 8;
      short8 a[4], b[4];
      #pragma unroll
      for (int i = 0; i < 4; ++i) a[i] = *(const short8*)&As[wm * 64 + i * 16 + l15][ko];
      #pragma unroll
      for (int j = 0; j < 4; ++j) b[j] = *(const short8*)&Bs[wn * 64 + j * 16 + l15][ko];
      #pragma unroll
      for (int i = 0; i < 4; ++i)
        #pragma unroll
        for (int j = 0; j < 4; ++j)
          acc[i][j] = __builtin_amdgcn_mfma_f32_16x16x32_bf16(a[i], b[j], acc[i][j], 0, 0, 0);
    }
    __syncthreads();
  }
  // D: col(l15)=pixel, row(quad*4+reg)=o
  float sq[4] = {0.f, 0.f, 0.f, 0.f};
  #pragma unroll
  for (int i = 0; i < 4; ++i) {
    int ob = row0 + wm * 64 + i * 16 + quad * 4;
    float4 bv = *(const float4*)&bias[ob];
    #pragma unroll
    for (int j = 0; j < 4; ++j) {
      int pix = col0 + wn * 64 + j * 16 + l15;
      float v0 = acc[i][j][0] + bv.x, v1 = acc[i][j][1] + bv.y;
      float v2 = acc[i][j][2] + bv.z, v3 = acc[i][j][3] + bv.w;
      ushort4 u; u.x = f2bf(v0); u.y = f2bf(v1); u.z = f2bf(v2); u.w = f2bf(v3);
      *(ushort4*)&phi_t[(size_t)pix * ODIM + ob] = u;
      sq[j] += v0 * v0 + v1 * v1 + v2 * v2 + v3 * v3;
    }
  }
  #pragma unroll
  for (int j = 0; j < 4; ++j) {
    sq[j] += __shfl_xor(sq[j], 16, 64);
    sq[j] += __shfl_xor(sq[j], 32, 64);
  }
  if (quad == 0) {
    #pragma unroll
    for (int j = 0; j < 4; ++j)
      atomicAdd(&feat[col0 + wn * 64 + j * 16 + l15], sq[j]);
  }
}

// ---------------- GEMM2 + fused top-3 (round-4 staging, round-6 spill-free epilogue) ----------------
__global__ __launch_bounds__(256) void gemm2_mfma(const uint16_t* __restrict__ phi_t, const uint16_t* __restrict__ Ct,
                                                  const float* __restrict__ cent, float* __restrict__ part) {
  __shared__ uint16_t As[128][72];
  __shared__ uint16_t Bs[128][72];
  int t = threadIdx.x;
  int row0 = blockIdx.y * 128;     // pixel
  int col0 = blockIdx.x * 128;     // centroid
  int lane = t & 63, wv = t >> 6, wm = wv & 1, wn = wv >> 1;
  int l15 = lane & 15, quad = lane >> 4;
  f32x4 acc[4][4] = {};
  for (int k0 = 0; k0 < ODIM; k0 += 64) {
    #pragma unroll
    for (int it = 0; it < 4; ++it) {
      int idx = it * 256 + t;
      int r = idx >> 3, kc = idx & 7;
      *(uint4*)&As[r][kc * 8] = *(const uint4*)&phi_t[(size_t)(row0 + r) * ODIM + k0 + kc * 8];
      *(uint4*)&Bs[r][kc * 8] = *(const uint4*)&Ct[(size_t)(col0 + r) * ODIM + k0 + kc * 8];
    }
    __syncthreads();
    #pragma unroll
    for (int kk = 0; kk < 2; ++kk) {
      int ko = kk * 32 + quad * 8;
      short8 a[4], b[4];
      #pragma unroll
      for (int i = 0; i < 4; ++i) a[i] = *(const short8*)&As[wm * 64 + i * 16 + l15][ko];
      #pragma unroll
      for (int j = 0; j < 4; ++j) b[j] = *(const short8*)&Bs[wn * 64 + j * 16 + l15][ko];
      #pragma unroll
      for (int i = 0; i < 4; ++i)
        #pragma unroll
        for (int j = 0; j < 4; ++j)
          acc[i][j] = __builtin_amdgcn_mfma_f32_16x16x32_bf16(a[i], b[j], acc[i][j], 0, 0, 0);
    }
    __syncthreads();
  }
  // D: col(l15)=centroid q, row(quad*4+reg)=pixel p. Pixel-sequential top-3 (no spill).
  float cv0 = cent[col0 + wn * 64 +  0 + l15];
  float cv1 = cent[col0 + wn * 64 + 16 + l15];
  float cv2 = cent[col0 + wn * 64 + 32 + l15];
  float cv3 = cent[col0 + wn * 64 + 48 + l15];
  int cb = blockIdx.x * 2 + wn;                  // [0,50)
  #pragma unroll
  for (int i = 0; i < 4; ++i) {
    #pragma unroll
    for (int r = 0; r < 4; ++r) {
      float t0 = 1e30f, t1 = 1e30f, t2 = 1e30f;
      ins3(cv0 - 2.f * acc[i][0][r], t0, t1, t2);
      ins3(cv1 - 2.f * acc[i][1][r], t0, t1, t2);
      ins3(cv2 - 2.f * acc[i][2][r], t0, t1, t2);
      ins3(cv3 - 2.f * acc[i][3][r], t0, t1, t2);
      #pragma unroll
      for (int m = 1; m <= 8; m <<= 1) {
        float u0 = __shfl_xor(t0, m, 64);
        float u1 = __shfl_xor(t1, m, 64);
        float u2 = __shfl_xor(t2, m, 64);
        ins3(u0, t0, t1, t2); ins3(u1, t0, t1, t2); ins3(u2, t0, t1, t2);
      }
      if (l15 == 0) {
        int p = row0 + wm * 64 + i * 16 + quad * 4 + r;
        float* pp = part + ((size_t)p * 50 + cb) * 3;
        pp[0] = t0; pp[1] = t1; pp[2] = t2;
      }
    }
  }
}

// ---------------- merge 50 partial top-3 + softmin score, one wave per row ----------------
__global__ __launch_bounds__(256) void merge_score(const float* __restrict__ part, const float* __restrict__ feat,
                                                   float* __restrict__ out, int b) {
  int t = threadIdx.x, lane = t & 63, wv = t >> 6;
  int row = blockIdx.x * 4 + wv;                   // 784*4 = 3136
  float t0 = 1e30f, t1 = 1e30f, t2 = 1e30f;
  if (lane < 50) {
    const float* p = part + ((size_t)row * 50 + lane) * 3;
    ins3(p[0], t0, t1, t2); ins3(p[1], t0, t1, t2); ins3(p[2], t0, t1, t2);
  }
  #pragma unroll
  for (int m = 1; m < 64; m <<= 1) {
    float u0 = __shfl_xor(t0, m, 64);
    float u1 = __shfl_xor(t1, m, 64);
    float u2 = __shfl_xor(t2, m, 64);
    ins3(u0, t0, t1, t2); ins3(u1, t0, t1, t2); ins3(u2, t0, t1, t2);
  }
  if (lane == 0) {
    float ft = feat[row];
    float v0 = sqrtf(fmaxf(ft + t0, 0.f));
    float v1 = sqrtf(fmaxf(ft + t1, 0.f));
    float v2 = sqrtf(fmaxf(ft + t2, 0.f));
    float w0 = 1.f / (1.f + expf(v0 - v1) + expf(v0 - v2));
    out[b * HWo + row] = v0 * w0;
  }
}

// ---------------- launch ----------------
extern "C" void kernel_launch(void* const* d_in, const int* in_sizes, int n_in,
                              void* d_out, int out_size, void* d_ws, size_t ws_size,
                              hipStream_t stream) {
  const float* p1   = (const float*)d_in[0];
  const float* p2   = (const float*)d_in[1];
  const float* p3   = (const float*)d_in[2];
  const float* Wm   = (const float*)d_in[3];
  const float* bias = (const float*)d_in[4];
  const float* Cm   = (const float*)d_in[5];
  float* out = (float*)d_out;

  // workspace (~49.1 MB), 256B-aligned slices
  char* ws = (char*)d_ws;
  size_t off = 0;
  uint16_t* Wh     = (uint16_t*)(ws + off); off += (size_t)ODIM * KP1 * 2;          // 6,651,904
  uint16_t* Ct     = (uint16_t*)(ws + off); off += (size_t)NP * ODIM * 2;           // 11,468,800
  float*    cent   = (float*)(ws + off);    off += 16384;
  float*    feat   = (float*)(ws + off);    off += 16384;
  float*    part   = (float*)(ws + off);    off += (size_t)NP * 50 * 3 * 4;         // 1,920,000
  float*    pooled = (float*)(ws + off);    off += (size_t)(P1SZ + P2SZ + P3SZ) * 4;// 5,619,712
  uint16_t* xcb    = (uint16_t*)(ws + off); off += (size_t)NP * KP1 * 2;            // 11,878,400
  uint16_t* phi_t  = (uint16_t*)(ws + off); off += (size_t)NP * ODIM * 2;           // 11,468,800

  convW_kernel<<<(ODIM * KP1) / 256, 256, 0, stream>>>(Wm, Wh);
  convC_kernel<<<(NCENT * ODIM) / 256, 256, 0, stream>>>(Cm, Ct);
  cent_kernel<<<NP / 4, 256, 0, stream>>>(Ct, cent);

  for (int b = 0; b < NB; ++b) {
    pool_kernel<<<(P1SZ + P2SZ + P3SZ) / 256, 256, 0, stream>>>(p1, p2, p3, pooled, b);
    assemble_kernel<<<(HWo * KP1) / 256, 256, 0, stream>>>(pooled, xcb, feat);
    gemm1_mfma<<<dim3(NP / 128, ODIM / 128), 256, 0, stream>>>(Wh, bias, xcb, phi_t, feat);
    gemm2_mfma<<<dim3(NP / 128, NP / 128), 256, 0, stream>>>(phi_t, Ct, cent, part);
    merge_score<<<784, 256, 0, stream>>>(part, feat, out, b);
  }
}

// Round 9
// 2119.699 us; speedup vs baseline: 2.1102x; 1.1988x over previous
//
#include <hip/hip_runtime.h>
#include <math.h>
#include <stdint.h>

typedef float f32x4 __attribute__((ext_vector_type(4)));
typedef short short8 __attribute__((ext_vector_type(8)));

static constexpr int HWo   = 3136;   // 56*56
static constexpr int NB    = 8;
static constexpr int NP    = 3200;   // padded pixel/centroid count (25*128)
static constexpr int KDIM  = 1794;   // 1792 + 2 coord channels
static constexpr int KP1   = 1856;   // gemm1 K padded to 29*64
static constexpr int ODIM  = 1792;   // gemm2 K = 28*64
static constexpr int NCENT = 3136;

__device__ __forceinline__ uint16_t f2bf(float f) {
  union { float f; uint32_t u; } v; v.f = f;
  uint32_t u = v.u;
  return (uint16_t)((u + 0x7FFFu + ((u >> 16) & 1u)) >> 16);   // RNE
}
__device__ __forceinline__ float bf2f(uint16_t h) {
  union { uint32_t u; float f; } v; v.u = ((uint32_t)h) << 16;
  return v.f;
}

// ---------------- one-time converts ----------------
__global__ __launch_bounds__(256) void convW_kernel(const float* __restrict__ W, uint16_t* __restrict__ Wh) {
  int idx = blockIdx.x * 256 + threadIdx.x;          // 1792*1856 exact
  int o = idx / KP1, k = idx % KP1;
  float v = (k < KDIM) ? W[(size_t)o * KDIM + k] : 0.f;
  Wh[idx] = f2bf(v);
}

__global__ __launch_bounds__(256) void convC_kernel(const float* __restrict__ C, uint16_t* __restrict__ Ct) {
  int idx = blockIdx.x * 256 + threadIdx.x;          // 3136*1792 exact
  int j = idx / ODIM, o = idx % ODIM;
  Ct[(size_t)j * ODIM + o] = f2bf(C[(size_t)o * NCENT + j]);
}

// cent[j] = |C_col_j|^2 for j<3136, 1e30 sentinel for padded rows
__global__ __launch_bounds__(256) void cent_kernel(const uint16_t* __restrict__ Ct, float* __restrict__ cent) {
  int t = threadIdx.x, lane = t & 63, wv = t >> 6;
  int row = blockIdx.x * 4 + wv;                     // 800 blocks -> 3200 rows
  if (row >= NCENT) { if (lane == 0) cent[row] = 1e30f; return; }
  const uint32_t* p = (const uint32_t*)(Ct + (size_t)row * ODIM);
  float s = 0.f;
  #pragma unroll
  for (int it = 0; it < 14; ++it) {
    uint32_t u = p[it * 64 + lane];
    float a = bf2f((uint16_t)(u & 0xFFFF)), b = bf2f((uint16_t)(u >> 16));
    s += a * a + b * b;
  }
  #pragma unroll
  for (int m = 1; m < 64; m <<= 1) s += __shfl_xor(s, m, 64);
  if (lane == 0) cent[row] = s;
}

// ---------------- pooling (all 3 levels, native res, fp32) ----------------
static constexpr int P1SZ = 256 * 3136;
static constexpr int P2SZ = 512 * 784;
static constexpr int P3SZ = 1024 * 196;

__device__ __forceinline__ float pool9f(const float* __restrict__ p, int S, int y, int x) {
  float s = 0.f;
  for (int dy = -1; dy <= 1; ++dy) {
    int yy = y + dy; if (yy < 0 || yy >= S) continue;
    for (int dx = -1; dx <= 1; ++dx) {
      int xx = x + dx; if (xx < 0 || xx >= S) continue;
      s += p[yy * S + xx];
    }
  }
  return s * (1.f / 9.f);
}

__global__ __launch_bounds__(256) void pool_kernel(const float* __restrict__ p1, const float* __restrict__ p2,
                                                   const float* __restrict__ p3, float* __restrict__ pooled, int b) {
  int idx = blockIdx.x * 256 + threadIdx.x;          // 1404928 exact
  const float* src; int S, loc;
  if (idx < P1SZ)              { src = p1 + (size_t)b * P1SZ; S = 56; loc = idx; }
  else if (idx < P1SZ + P2SZ)  { src = p2 + (size_t)b * P2SZ; S = 28; loc = idx - P1SZ; }
  else                         { src = p3 + (size_t)b * P3SZ; S = 14; loc = idx - P1SZ - P2SZ; }
  int c = loc / (S * S), hw = loc % (S * S);
  pooled[idx] = pool9f(src + (size_t)c * S * S, S, hw / S, hw % S);
}

// ---------------- assemble xcb bf16 [3200][1856] pixel-major; also zero feat ----------------
__global__ __launch_bounds__(256) void assemble_kernel(const float* __restrict__ pooled, uint16_t* __restrict__ xcb,
                                                       float* __restrict__ feat) {
  int idx = blockIdx.x * 256 + threadIdx.x;          // 3136*1856 exact
  if (idx < NP) feat[idx] = 0.f;                     // zero feat for gemm1 atomics
  int i = idx / KP1, ch = idx % KP1;
  int x = i % 56, y = i / 56;
  float v;
  if (ch < 256) {
    v = pooled[ch * 3136 + i];
  } else if (ch < 1792) {
    const float* base; int S; float scale, shift;
    if (ch < 768) { base = pooled + P1SZ + (ch - 256) * 784;          S = 28; scale = 0.5f;  shift = -0.25f;  }
    else          { base = pooled + P1SZ + P2SZ + (ch - 768) * 196;   S = 14; scale = 0.25f; shift = -0.375f; }
    float sx = x * scale + shift, sy = y * scale + shift;
    float fx0 = floorf(sx), fy0 = floorf(sy);
    float fx = sx - fx0, fy = sy - fy0;
    int x0 = (int)fx0, y0 = (int)fy0, x1 = x0 + 1, y1 = y0 + 1;
    x0 = x0 < 0 ? 0 : x0; x1 = x1 > S - 1 ? S - 1 : x1;
    y0 = y0 < 0 ? 0 : y0; y1 = y1 > S - 1 ? S - 1 : y1;
    float v00 = base[y0 * S + x0], v01 = base[y0 * S + x1];
    float v10 = base[y1 * S + x0], v11 = base[y1 * S + x1];
    v = (1.f - fy) * ((1.f - fx) * v00 + fx * v01) + fy * ((1.f - fx) * v10 + fx * v11);
  } else if (ch == 1792) v = -1.f + 2.f * x / 55.f;
  else if (ch == 1793)   v = -1.f + 2.f * y / 55.f;
  else                   v = 0.f;                    // K padding: MUST be zero
  xcb[idx] = f2bf(v);
}

__device__ __forceinline__ void ins3(float v, float& a, float& b, float& c) {
  if (v < c) {
    if (v < b) { c = b; if (v < a) { b = a; a = v; } else { b = v; } }
    else { c = v; }
  }
}

// ---------------- GEMM1: phi_t[i][o] = W[o][:]·xc[i][:] + bias[o]; feat[i] += |phi_i|^2 ----------------
__global__ __launch_bounds__(256) void gemm1_mfma(const uint16_t* __restrict__ Wh, const float* __restrict__ bias,
                                                  const uint16_t* __restrict__ xcb, uint16_t* __restrict__ phi_t,
                                                  float* __restrict__ feat) {
  __shared__ uint16_t As[128][72];   // +8 pad: benign ~2.4% store-conflict tax (measured r4)
  __shared__ uint16_t Bs[128][72];
  int t = threadIdx.x;
  int row0 = blockIdx.y * 128;     // o
  int col0 = blockIdx.x * 128;     // pixel
  int lane = t & 63, wv = t >> 6, wm = wv & 1, wn = wv >> 1;
  int l15 = lane & 15, quad = lane >> 4;
  f32x4 acc[4][4] = {};
  for (int k0 = 0; k0 < KP1; k0 += 64) {
    #pragma unroll
    for (int it = 0; it < 4; ++it) {
      int idx = it * 256 + t;
      int r = idx >> 3, kc = idx & 7;
      *(uint4*)&As[r][kc * 8] = *(const uint4*)&Wh[(size_t)(row0 + r) * KP1 + k0 + kc * 8];
      *(uint4*)&Bs[r][kc * 8] = *(const uint4*)&xcb[(size_t)(col0 + r) * KP1 + k0 + kc * 8];
    }
    __syncthreads();
    #pragma unroll
    for (int kk = 0; kk < 2; ++kk) {
      int ko = kk * 32 + quad * 8;
      short8 a[4], b[4];
      #pragma unroll
      for (int i = 0; i < 4; ++i) a[i] = *(const short8*)&As[wm * 64 + i * 16 + l15][ko];
      #pragma unroll
      for (int j = 0; j < 4; ++j) b[j] = *(const short8*)&Bs[wn * 64 + j * 16 + l15][ko];
      #pragma unroll
      for (int i = 0; i < 4; ++i)
        #pragma unroll
        for (int j = 0; j < 4; ++j)
          acc[i][j] = __builtin_amdgcn_mfma_f32_16x16x32_bf16(a[i], b[j], acc[i][j], 0, 0, 0);
    }
    __syncthreads();
  }
  // D: col(l15)=pixel, row(quad*4+reg)=o
  float sq[4] = {0.f, 0.f, 0.f, 0.f};
  #pragma unroll
  for (int i = 0; i < 4; ++i) {
    int ob = row0 + wm * 64 + i * 16 + quad * 4;
    float4 bv = *(const float4*)&bias[ob];
    #pragma unroll
    for (int j = 0; j < 4; ++j) {
      int pix = col0 + wn * 64 + j * 16 + l15;
      float v0 = acc[i][j][0] + bv.x, v1 = acc[i][j][1] + bv.y;
      float v2 = acc[i][j][2] + bv.z, v3 = acc[i][j][3] + bv.w;
      ushort4 u; u.x = f2bf(v0); u.y = f2bf(v1); u.z = f2bf(v2); u.w = f2bf(v3);
      *(ushort4*)&phi_t[(size_t)pix * ODIM + ob] = u;
      sq[j] += v0 * v0 + v1 * v1 + v2 * v2 + v3 * v3;
    }
  }
  #pragma unroll
  for (int j = 0; j < 4; ++j) {
    sq[j] += __shfl_xor(sq[j], 16, 64);
    sq[j] += __shfl_xor(sq[j], 32, 64);
  }
  if (quad == 0) {
    #pragma unroll
    for (int j = 0; j < 4; ++j)
      atomicAdd(&feat[col0 + wn * 64 + j * 16 + l15], sq[j]);
  }
}

// ---------------- GEMM2 + fused top-3 via LDS scratch (no shuffles, compact code) ----------------
__global__ __launch_bounds__(256) void gemm2_mfma(const uint16_t* __restrict__ phi_t, const uint16_t* __restrict__ Ct,
                                                  const float* __restrict__ cent, float* __restrict__ part) {
  __shared__ __align__(16) char smem[36864];         // union: K-loop tiles / epilogue key scratch
  uint16_t (*As)[72] = (uint16_t(*)[72])smem;
  uint16_t (*Bs)[72] = (uint16_t(*)[72])(smem + 18432);
  int t = threadIdx.x;
  int row0 = blockIdx.y * 128;     // pixel
  int col0 = blockIdx.x * 128;     // centroid
  int lane = t & 63, wv = t >> 6, wm = wv & 1, wn = wv >> 1;
  int l15 = lane & 15, quad = lane >> 4;
  f32x4 acc[4][4] = {};
  for (int k0 = 0; k0 < ODIM; k0 += 64) {
    #pragma unroll
    for (int it = 0; it < 4; ++it) {
      int idx = it * 256 + t;
      int r = idx >> 3, kc = idx & 7;
      *(uint4*)&As[r][kc * 8] = *(const uint4*)&phi_t[(size_t)(row0 + r) * ODIM + k0 + kc * 8];
      *(uint4*)&Bs[r][kc * 8] = *(const uint4*)&Ct[(size_t)(col0 + r) * ODIM + k0 + kc * 8];
    }
    __syncthreads();
    #pragma unroll
    for (int kk = 0; kk < 2; ++kk) {
      int ko = kk * 32 + quad * 8;
      short8 a[4], b[4];
      #pragma unroll
      for (int i = 0; i < 4; ++i) a[i] = *(const short8*)&As[wm * 64 + i * 16 + l15][ko];
      #pragma unroll
      for (int j = 0; j < 4; ++j) b[j] = *(const short8*)&Bs[wn * 64 + j * 16 + l15][ko];
      #pragma unroll
      for (int i = 0; i < 4; ++i)
        #pragma unroll
        for (int j = 0; j < 4; ++j)
          acc[i][j] = __builtin_amdgcn_mfma_f32_16x16x32_bf16(a[i], b[j], acc[i][j], 0, 0, 0);
    }
    __syncthreads();
  }
  // D: col(l15)=centroid q, row(quad*4+reg)=pixel p.
  // Epilogue: per column-half phase, dump keys to LDS [128][66] then 128 threads
  // scan one pixel-row each (rolled loop, runtime indices). No shuffles, ~2KB code.
  float cv0 = cent[col0 + wn * 64 +  0 + l15];
  float cv1 = cent[col0 + wn * 64 + 16 + l15];
  float cv2 = cent[col0 + wn * 64 + 32 + l15];
  float cv3 = cent[col0 + wn * 64 + 48 + l15];
  float* sk = (float*)smem;                          // 128*66*4 = 33792 B <= 36864
  #pragma unroll 1
  for (int p = 0; p < 2; ++p) {
    if (wn == p) {
      #pragma unroll
      for (int i = 0; i < 4; ++i) {
        #pragma unroll
        for (int r = 0; r < 4; ++r) {
          int pix = wm * 64 + i * 16 + quad * 4 + r;
          sk[pix * 66 +  0 + l15] = cv0 - 2.f * acc[i][0][r];
          sk[pix * 66 + 16 + l15] = cv1 - 2.f * acc[i][1][r];
          sk[pix * 66 + 32 + l15] = cv2 - 2.f * acc[i][2][r];
          sk[pix * 66 + 48 + l15] = cv3 - 2.f * acc[i][3][r];
        }
      }
    }
    __syncthreads();
    if (t < 128) {
      float t0 = 1e30f, t1 = 1e30f, t2 = 1e30f;
      #pragma unroll 4
      for (int c = 0; c < 64; ++c) ins3(sk[t * 66 + c], t0, t1, t2);
      float* pp = part + ((size_t)(row0 + t) * 50 + blockIdx.x * 2 + p) * 3;
      pp[0] = t0; pp[1] = t1; pp[2] = t2;
    }
    __syncthreads();
  }
}

// ---------------- merge 50 partial top-3 + softmin score, one wave per row ----------------
__global__ __launch_bounds__(256) void merge_score(const float* __restrict__ part, const float* __restrict__ feat,
                                                   float* __restrict__ out, int b) {
  int t = threadIdx.x, lane = t & 63, wv = t >> 6;
  int row = blockIdx.x * 4 + wv;                   // 784*4 = 3136
  float t0 = 1e30f, t1 = 1e30f, t2 = 1e30f;
  if (lane < 50) {
    const float* p = part + ((size_t)row * 50 + lane) * 3;
    ins3(p[0], t0, t1, t2); ins3(p[1], t0, t1, t2); ins3(p[2], t0, t1, t2);
  }
  #pragma unroll
  for (int m = 1; m < 64; m <<= 1) {
    float u0 = __shfl_xor(t0, m, 64);
    float u1 = __shfl_xor(t1, m, 64);
    float u2 = __shfl_xor(t2, m, 64);
    ins3(u0, t0, t1, t2); ins3(u1, t0, t1, t2); ins3(u2, t0, t1, t2);
  }
  if (lane == 0) {
    float ft = feat[row];
    float v0 = sqrtf(fmaxf(ft + t0, 0.f));
    float v1 = sqrtf(fmaxf(ft + t1, 0.f));
    float v2 = sqrtf(fmaxf(ft + t2, 0.f));
    float w0 = 1.f / (1.f + expf(v0 - v1) + expf(v0 - v2));
    out[b * HWo + row] = v0 * w0;
  }
}

// ---------------- launch ----------------
extern "C" void kernel_launch(void* const* d_in, const int* in_sizes, int n_in,
                              void* d_out, int out_size, void* d_ws, size_t ws_size,
                              hipStream_t stream) {
  const float* p1   = (const float*)d_in[0];
  const float* p2   = (const float*)d_in[1];
  const float* p3   = (const float*)d_in[2];
  const float* Wm   = (const float*)d_in[3];
  const float* bias = (const float*)d_in[4];
  const float* Cm   = (const float*)d_in[5];
  float* out = (float*)d_out;

  // workspace (~49.1 MB), 256B-aligned slices
  char* ws = (char*)d_ws;
  size_t off = 0;
  uint16_t* Wh     = (uint16_t*)(ws + off); off += (size_t)ODIM * KP1 * 2;          // 6,651,904
  uint16_t* Ct     = (uint16_t*)(ws + off); off += (size_t)NP * ODIM * 2;           // 11,468,800
  float*    cent   = (float*)(ws + off);    off += 16384;
  float*    feat   = (float*)(ws + off);    off += 16384;
  float*    part   = (float*)(ws + off);    off += (size_t)NP * 50 * 3 * 4;         // 1,920,000
  float*    pooled = (float*)(ws + off);    off += (size_t)(P1SZ + P2SZ + P3SZ) * 4;// 5,619,712
  uint16_t* xcb    = (uint16_t*)(ws + off); off += (size_t)NP * KP1 * 2;            // 11,878,400
  uint16_t* phi_t  = (uint16_t*)(ws + off); off += (size_t)NP * ODIM * 2;           // 11,468,800

  convW_kernel<<<(ODIM * KP1) / 256, 256, 0, stream>>>(Wm, Wh);
  convC_kernel<<<(NCENT * ODIM) / 256, 256, 0, stream>>>(Cm, Ct);
  cent_kernel<<<NP / 4, 256, 0, stream>>>(Ct, cent);

  for (int b = 0; b < NB; ++b) {
    pool_kernel<<<(P1SZ + P2SZ + P3SZ) / 256, 256, 0, stream>>>(p1, p2, p3, pooled, b);
    assemble_kernel<<<(HWo * KP1) / 256, 256, 0, stream>>>(pooled, xcb, feat);
    gemm1_mfma<<<dim3(NP / 128, ODIM / 128), 256, 0, stream>>>(Wh, bias, xcb, phi_t, feat);
    gemm2_mfma<<<dim3(NP / 128, NP / 128), 256, 0, stream>>>(phi_t, Ct, cent, part);
    merge_score<<<784, 256, 0, stream>>>(part, feat, out, b);
  }
}